// Round 1
// baseline (3725.462 us; speedup 1.0000x reference)
//
#include <hip/hip_runtime.h>
#include <math.h>

// Problem constants (from reference)
#define TPB 256
constexpr int B_    = 16;
constexpr int C_    = 4;
constexpr int L_    = 1000;
constexpr int K_    = 64;
constexpr int LK    = 15;
constexpr int NOUT  = 986;            // (1000-15)/1+1
constexpr int NPOS  = B_ * NOUT;      // 15776 positions per kernel-k

// LDS layout (floats)
constexpr int ACT_FLOATS  = 86 * TPB;     // 22016: act[d][tid], d-major, conflict-free
constexpr int WBUF_FLOATS = 86 * 88;      // 7568: max padded layer weights (layer2: 86x86 -> 86x88)
constexpr int BBUF_FLOATS = 88;
constexpr int HBUF_FLOATS = 64;           // head_w (59) + head_b
constexpr int SMEM_FLOATS = ACT_FLOATS + WBUF_FLOATS + BBUF_FLOATS + HBUF_FLOATS;
constexpr size_t SMEM_BYTES = (size_t)SMEM_FLOATS * sizeof(float);

__device__ __forceinline__ float gelu_exact(float v) {
    // exact gelu: x * 0.5 * (1 + erf(x / sqrt(2)))
    return 0.5f * v * (1.0f + erff(v * 0.70710678118654752f));
}

// One MLP layer for one kernel-k: stage weights into LDS, per-thread dot
// products with register accumulator (fully unrolled over DO), gelu, write
// activations back into this thread's private LDS column.
template<int DI, int DO, int DOP, bool LAST>
__device__ __forceinline__ void layer_compute(
    const float* __restrict__ wg, const float* __restrict__ bg,
    const float* __restrict__ hw, const float* __restrict__ hb,
    int k, int tid,
    float* __restrict__ act, float* __restrict__ wbuf,
    float* __restrict__ bbuf, float* __restrict__ hbuf,
    float* __restrict__ out, int b, int pos, bool valid)
{
    __syncthreads();  // previous layer's wbuf consumers done
    const float* wsrc = wg + (size_t)k * (DI * DO);
    for (int i = tid; i < DI * DO; i += TPB) {
        int d = i / DO;
        int e = i - d * DO;
        wbuf[d * DOP + e] = wsrc[i];   // rows padded to DOP (16B multiple) for b128 broadcast reads
    }
    if (tid < DO) bbuf[tid] = bg[k * DO + tid];
    if (LAST) {
        if (tid < 59) hbuf[tid] = hw[tid];
        if (tid == 59) hbuf[59] = hb[0];
    }
    __syncthreads();

    float acc[DO];
#pragma unroll
    for (int e = 0; e < DO; e++) acc[e] = bbuf[e];

    for (int d = 0; d < DI; d++) {
        float a = act[d * TPB + tid];        // lane-consecutive: conflict-free (2-way aliasing is free)
#pragma unroll
        for (int e = 0; e < DO; e++) {
            acc[e] += a * wbuf[d * DOP + e]; // same-address broadcast; vectorizes to ds_read_b128
        }
    }

    if (!LAST) {
#pragma unroll
        for (int e = 0; e < DO; e++) {
            act[e * TPB + tid] = gelu_exact(acc[e]);
        }
    } else {
        float r = hbuf[59];  // head_b
#pragma unroll
        for (int e = 0; e < DO; e++) {
            r += gelu_exact(acc[e]) * hbuf[e];
        }
        if (valid) out[((size_t)b * K_ + k) * NOUT + pos] = r;
    }
}

__global__ __launch_bounds__(TPB, 1)
void conv_mlp_fused_kernel(
    const float* __restrict__ x,
    const float* __restrict__ w0, const float* __restrict__ b0,
    const float* __restrict__ w1, const float* __restrict__ b1,
    const float* __restrict__ w2, const float* __restrict__ b2,
    const float* __restrict__ w3, const float* __restrict__ b3,
    const float* __restrict__ w4, const float* __restrict__ b4,
    const float* __restrict__ hw, const float* __restrict__ hb,
    float* __restrict__ out)
{
    extern __shared__ float smem[];
    float* act  = smem;
    float* wbuf = smem + ACT_FLOATS;
    float* bbuf = wbuf + WBUF_FLOATS;
    float* hbuf = bbuf + BBUF_FLOATS;

    const int tid = threadIdx.x;
    const int k   = blockIdx.x;
    const int p   = blockIdx.y * TPB + tid;
    const bool valid = (p < NPOS);
    const int pc  = valid ? p : (NPOS - 1);
    const int b   = pc / NOUT;
    const int pos = pc - b * NOUT;

    // Layer-0 input: window gather x[b, c, pos+j] -> act[(c*15+j)][tid]
    const float* xb = x + (size_t)b * (C_ * L_);
#pragma unroll
    for (int c = 0; c < C_; c++) {
#pragma unroll
        for (int j = 0; j < LK; j++) {
            act[(c * LK + j) * TPB + tid] = xb[c * L_ + pos + j];
        }
    }

    layer_compute<60, 72, 72, false>(w0, b0, nullptr, nullptr, k, tid, act, wbuf, bbuf, hbuf, out, b, pos, valid);
    layer_compute<72, 86, 88, false>(w1, b1, nullptr, nullptr, k, tid, act, wbuf, bbuf, hbuf, out, b, pos, valid);
    layer_compute<86, 86, 88, false>(w2, b2, nullptr, nullptr, k, tid, act, wbuf, bbuf, hbuf, out, b, pos, valid);
    layer_compute<86, 71, 72, false>(w3, b3, nullptr, nullptr, k, tid, act, wbuf, bbuf, hbuf, out, b, pos, valid);
    layer_compute<71, 59, 60, true >(w4, b4, hw, hb,           k, tid, act, wbuf, bbuf, hbuf, out, b, pos, valid);
}

extern "C" void kernel_launch(void* const* d_in, const int* in_sizes, int n_in,
                              void* d_out, int out_size, void* d_ws, size_t ws_size,
                              hipStream_t stream) {
    const float* x  = (const float*)d_in[0];
    const float* w0 = (const float*)d_in[1];  const float* b0 = (const float*)d_in[2];
    const float* w1 = (const float*)d_in[3];  const float* b1 = (const float*)d_in[4];
    const float* w2 = (const float*)d_in[5];  const float* b2 = (const float*)d_in[6];
    const float* w3 = (const float*)d_in[7];  const float* b3 = (const float*)d_in[8];
    const float* w4 = (const float*)d_in[9];  const float* b4 = (const float*)d_in[10];
    const float* hw = (const float*)d_in[11]; const float* hb = (const float*)d_in[12];
    float* out = (float*)d_out;

    // gfx950 allows up to 160 KiB LDS per workgroup; opt in for >64 KiB dynamic.
    (void)hipFuncSetAttribute((const void*)conv_mlp_fused_kernel,
                              hipFuncAttributeMaxDynamicSharedMemorySize,
                              (int)SMEM_BYTES);

    dim3 grid(K_, (NPOS + TPB - 1) / TPB);   // 64 x 62
    conv_mlp_fused_kernel<<<grid, TPB, SMEM_BYTES, stream>>>(
        x, w0, b0, w1, b1, w2, b2, w3, b3, w4, b4, hw, hb, out);
}

// Round 2
// 376.012 us; speedup vs baseline: 9.9078x; 9.9078x over previous
//
#include <hip/hip_runtime.h>

typedef _Float16 f16;
typedef __attribute__((ext_vector_type(8))) _Float16 f16x8;
typedef __attribute__((ext_vector_type(4))) float f32x4;

constexpr int C_ = 4, L_ = 1000, K_ = 64, NOUT = 986, NPOS = 16 * 986; // 15776
constexpr int MTB  = 128;                       // rows per block
constexpr int NBLK = (NPOS + MTB - 1) / MTB;    // 124
constexpr int AST  = 104;                       // act/weight row stride in fp16 elems (208 B: 16B-aligned, 2-way banks)
constexpr int ACT_EL  = MTB * AST;              // 13312
constexpr int WBUF_EL = 96 * AST;               // 9984
constexpr size_t SMEM_BYTES = (size_t)(2 * ACT_EL + WBUF_EL) * sizeof(f16); // 73216 B -> 2 blocks/CU

// ws layout: per layer l, per k: WROWS[l] rows x AST cols of fp16 W^T (row = out-idx e, col = in-idx d), zero-padded
constexpr size_t WOFF[5]  = {0, 638976, 1277952, 1916928, 2555904};
constexpr int    WROWS[5] = {96, 96, 96, 96, 64};
constexpr int    DIv[5]   = {60, 72, 86, 86, 71};
constexpr int    DOv[5]   = {72, 86, 86, 71, 59};
constexpr size_t WS_NEED_BYTES = (2555904 + (size_t)64 * 64 * AST) * sizeof(f16); // 5,963,776

__device__ __forceinline__ float gelu_f(float x) {
    // gelu tanh-form as x * sigmoid(2z), z = x*(c1 + c2*x^2); max |err| vs exact ~5e-4
    float x2 = x * x;
    float z  = x * __builtin_fmaf(0.0356774081f, x2, 0.7978845608f);
    float e  = __expf(-2.0f * z);
    return x * __builtin_amdgcn_rcpf(e + 1.0f);   // x->-inf: e->inf, rcp->0 => 0; x->+inf: e->0 => x
}

__device__ __forceinline__ void async_cp16(const f16* g, f16* l) {
    __builtin_amdgcn_global_load_lds((const __attribute__((address_space(1))) void*)g,
                                     (__attribute__((address_space(3))) void*)l, 16, 0, 0);
}

// copy chunks*16B global->LDS; LDS dest must be wave-uniform base + lane*16
__device__ __forceinline__ void stage_w(const f16* __restrict__ src, f16* __restrict__ dst,
                                        int chunks, int tid) {
    int wv64 = tid & ~63;
    for (int c0 = 0; c0 < chunks; c0 += 256) {
        int c = c0 + tid;
        if (c < chunks) async_cp16(src + (size_t)c * 8, dst + (size_t)(c0 + wv64) * 8);
    }
}

// K-loop: acc[MTN][NTN] (16x16 tiles), A from actin rows, B from W^T rows (shared k-mapping => correct dot)
template<int KSTEPS, int MTN, int NTN>
__device__ __forceinline__ void layer_mm(const f16* __restrict__ actin, const f16* __restrict__ wb,
                                         f32x4 (&acc)[MTN][NTN], int mtb, int ntb, int li, int q) {
#pragma unroll
    for (int mt = 0; mt < MTN; mt++)
#pragma unroll
        for (int nt = 0; nt < NTN; nt++) acc[mt][nt] = f32x4{0.f, 0.f, 0.f, 0.f};
#pragma unroll
    for (int ks = 0; ks < KSTEPS; ks++) {
        const int koff = ks * 32 + q * 8;
        f16x8 a[MTN], b[NTN];
#pragma unroll
        for (int mt = 0; mt < MTN; mt++)
            a[mt] = *(const f16x8*)(actin + ((mtb + mt) * 16 + li) * AST + koff);
#pragma unroll
        for (int nt = 0; nt < NTN; nt++)
            b[nt] = *(const f16x8*)(wb + ((ntb + nt) * 16 + li) * AST + koff);
#pragma unroll
        for (int nt = 0; nt < NTN; nt++)
#pragma unroll
            for (int mt = 0; mt < MTN; mt++)
                acc[mt][nt] = __builtin_amdgcn_mfma_f32_16x16x32_f16(a[mt], b[nt], acc[mt][nt], 0, 0, 0);
    }
}

// bias + gelu + fp16 store to actout. C/D layout: col = lane&15, row = (lane>>4)*4 + r (m89-verified, dtype-indep)
template<int MTN, int NTN>
__device__ __forceinline__ void epilogue4(f32x4 (&acc)[MTN][NTN], f16* __restrict__ actout,
                                          const float* __restrict__ bg, int k, int DO,
                                          int mtb, int ntb, int li, int q) {
    float bias[NTN];
#pragma unroll
    for (int nt = 0; nt < NTN; nt++) {
        int col = (ntb + nt) * 16 + li;
        bias[nt] = (col < DO) ? bg[k * DO + col] : 0.f;   // pad cols: gelu(0)=0 keeps K-pad zeros
    }
#pragma unroll
    for (int mt = 0; mt < MTN; mt++) {
        int rowb = (mtb + mt) * 16 + q * 4;
#pragma unroll
        for (int nt = 0; nt < NTN; nt++) {
            int col = (ntb + nt) * 16 + li;
#pragma unroll
            for (int r = 0; r < 4; r++)
                actout[(rowb + r) * AST + col] = (f16)gelu_f(acc[mt][nt][r] + bias[nt]);
        }
    }
}

// prep: fp32 w[k][d][e] -> fp16 W^T[k][e][d] with zero padding, coalesced both sides via LDS transpose
__global__ __launch_bounds__(256) void prep_weights(
    const float* __restrict__ w0, const float* __restrict__ w1, const float* __restrict__ w2,
    const float* __restrict__ w3, const float* __restrict__ w4, f16* __restrict__ ws) {
    __shared__ f16 wl[86 * 86];
    const int k = blockIdx.x, l = blockIdx.y, tid = threadIdx.x;
    const float* wsrc;
    switch (l) { case 0: wsrc = w0; break; case 1: wsrc = w1; break; case 2: wsrc = w2; break;
                 case 3: wsrc = w3; break; default: wsrc = w4; }
    const int DI = DIv[l], DO = DOv[l], RW = WROWS[l];
    wsrc += (size_t)k * DI * DO;
    for (int i = tid; i < DI * DO; i += 256) wl[i] = (f16)wsrc[i];
    __syncthreads();
    f16* dst = ws + WOFF[l] + (size_t)k * RW * AST;
    const int tot = RW * AST;
    for (int i = tid; i < tot; i += 256) {
        int e = i / AST, d = i - e * AST;
        f16 v = (f16)0.f;
        if (e < DO && d < DI) v = wl[d * DO + e];
        dst[i] = v;   // consecutive d -> coalesced
    }
}

__global__ __launch_bounds__(256, 2) void mlp_main(
    const float* __restrict__ x,
    const float* __restrict__ b0, const float* __restrict__ b1, const float* __restrict__ b2,
    const float* __restrict__ b3, const float* __restrict__ b4,
    const float* __restrict__ hw, const float* __restrict__ hb,
    const f16* __restrict__ ws, float* __restrict__ out) {
    extern __shared__ f16 smem[];
    f16* actA = smem;
    f16* actB = smem + ACT_EL;
    f16* wbuf = smem + 2 * ACT_EL;

    const int tid = threadIdx.x, k = blockIdx.x, mblk = blockIdx.y;
    const int wv = tid >> 6, lane = tid & 63, li = lane & 15, q = lane >> 4;
    const int base = mblk * MTB;

    // stage W0 async; overlap with x-gather
    stage_w(ws + WOFF[0] + (size_t)k * 96 * AST, wbuf, 96 * AST / 8, tid);

    // layer-0 activations: act[r][d], d = c*15+j in 0..59, cols 60..63 zeroed (K-pad)
    for (int i = tid; i < 64 * MTB; i += 256) {
        int d = i >> 7, r = i & 127;          // d wave-uniform, r lane-consecutive -> coalesced x reads
        int p = base + r; if (p > NPOS - 1) p = NPOS - 1;
        int b = p / NOUT, pos = p - b * NOUT;
        float v = 0.f;
        if (d < 60) { int c = d / 15, j = d - c * 15; v = x[(size_t)(b * C_ + c) * L_ + pos + j]; }
        actA[r * AST + d] = (f16)v;
    }
    __syncthreads();

    const int mtb = (wv & 1) * 4, ntb = (wv >> 1) * 3;   // wave = 4 M-tiles x 3 N-tiles
    f32x4 acc[4][3];

    layer_mm<2, 4, 3>(actA, wbuf, acc, mtb, ntb, li, q);            // L0: K=64
    epilogue4<4, 3>(acc, actB, b0, k, 72, mtb, ntb, li, q);
    __syncthreads();
    stage_w(ws + WOFF[1] + (size_t)k * 96 * AST, wbuf, 96 * AST / 8, tid);
    __syncthreads();
    layer_mm<3, 4, 3>(actB, wbuf, acc, mtb, ntb, li, q);            // L1: K=96
    epilogue4<4, 3>(acc, actA, b1, k, 86, mtb, ntb, li, q);
    __syncthreads();
    stage_w(ws + WOFF[2] + (size_t)k * 96 * AST, wbuf, 96 * AST / 8, tid);
    __syncthreads();
    layer_mm<3, 4, 3>(actA, wbuf, acc, mtb, ntb, li, q);            // L2
    epilogue4<4, 3>(acc, actB, b2, k, 86, mtb, ntb, li, q);
    __syncthreads();
    stage_w(ws + WOFF[3] + (size_t)k * 96 * AST, wbuf, 96 * AST / 8, tid);
    __syncthreads();
    layer_mm<3, 4, 3>(actB, wbuf, acc, mtb, ntb, li, q);            // L3 (NT=6 so cols 71..95 -> exact 0 for L4 K-pad)
    epilogue4<4, 3>(acc, actA, b3, k, 71, mtb, ntb, li, q);
    __syncthreads();
    stage_w(ws + WOFF[4] + (size_t)k * 64 * AST, wbuf, 64 * AST / 8, tid);
    __syncthreads();

    // L4 + fused head. Partition: wave = 2 M-tiles x all 4 N-tiles (head reduce stays intra-wave)
    f32x4 acc4[2][4];
    layer_mm<3, 2, 4>(actA, wbuf, acc4, 2 * wv, 0, li, q);

    float hwv[4], bv[4];
#pragma unroll
    for (int nt = 0; nt < 4; nt++) {
        int col = nt * 16 + li;
        hwv[nt] = (col < 59) ? hw[col] : 0.f;
        bv[nt]  = (col < 59) ? b4[k * 59 + col] : 0.f;
    }
    const float hb0 = hb[0];
#pragma unroll
    for (int mt = 0; mt < 2; mt++) {
        float sarr[4];
#pragma unroll
        for (int r = 0; r < 4; r++) {
            float part = 0.f;
#pragma unroll
            for (int nt = 0; nt < 4; nt++) part += gelu_f(acc4[mt][nt][r] + bv[nt]) * hwv[nt];
            part += __shfl_xor(part, 1, 16);
            part += __shfl_xor(part, 2, 16);
            part += __shfl_xor(part, 4, 16);
            part += __shfl_xor(part, 8, 16);
            sarr[r] = part + hb0;
        }
        if (li < 4) {
            int p = base + (2 * wv + mt) * 16 + q * 4 + li;
            if (p < NPOS) {
                int b = p / NOUT, pos = p - b * NOUT;
                float vv = (li == 0) ? sarr[0] : (li == 1) ? sarr[1] : (li == 2) ? sarr[2] : sarr[3];
                out[((size_t)(b * K_ + k)) * NOUT + pos] = vv;
            }
        }
    }
}

extern "C" void kernel_launch(void* const* d_in, const int* in_sizes, int n_in,
                              void* d_out, int out_size, void* d_ws, size_t ws_size,
                              hipStream_t stream) {
    const float* x  = (const float*)d_in[0];
    const float* w0 = (const float*)d_in[1];  const float* b0 = (const float*)d_in[2];
    const float* w1 = (const float*)d_in[3];  const float* b1 = (const float*)d_in[4];
    const float* w2 = (const float*)d_in[5];  const float* b2 = (const float*)d_in[6];
    const float* w3 = (const float*)d_in[7];  const float* b3 = (const float*)d_in[8];
    const float* w4 = (const float*)d_in[9];  const float* b4 = (const float*)d_in[10];
    const float* hw = (const float*)d_in[11]; const float* hb = (const float*)d_in[12];
    float* out = (float*)d_out;
    f16* ws = (f16*)d_ws;   // needs 5.96 MB

    (void)hipFuncSetAttribute((const void*)mlp_main,
                              hipFuncAttributeMaxDynamicSharedMemorySize, (int)SMEM_BYTES);

    prep_weights<<<dim3(K_, 5), 256, 0, stream>>>(w0, w1, w2, w3, w4, ws);
    // grid x=k: linear id = k + 64*m -> XCD = k%8: all m-blocks of a k share one XCD's L2 (weight reuse)
    mlp_main<<<dim3(K_, NBLK), 256, SMEM_BYTES, stream>>>(x, b0, b1, b2, b3, b4, hw, hb, ws, out);
}

// Round 4
// 314.331 us; speedup vs baseline: 11.8520x; 1.1962x over previous
//
#include <hip/hip_runtime.h>

typedef _Float16 f16;
typedef __attribute__((ext_vector_type(8))) _Float16 f16x8;
typedef __attribute__((ext_vector_type(2))) __fp16 hf16x2;   // native type of cvt_pkrtz
typedef __attribute__((ext_vector_type(4))) float f32x4;

constexpr int C_ = 4, L_ = 1000, K_ = 64, NOUT = 986, NPOS = 16 * 986; // 15776
constexpr int MTB  = 128;                       // positions per block
constexpr int NBLK = (NPOS + MTB - 1) / MTB;    // 124
constexpr int AST  = 104;                       // row stride (f16): 208 B, 16B-aligned
constexpr int ACT_EL  = MTB * AST;              // 13312 f16 (single in-place buffer)
constexpr int WBUF_EL = 96 * AST;               // 9984 f16
constexpr size_t SMEM_BYTES = (size_t)(ACT_EL + WBUF_EL) * 2 + (480 + 64) * 4; // 48768 B -> 3 blocks/CU

// ws: per layer l, per k: WROWS[l] rows x AST cols fp16 W^T (row=out e, col=in d), zero-padded
constexpr size_t WOFF[5]  = {0, 638976, 1277952, 1916928, 2555904};
constexpr int    WROWS[5] = {96, 96, 96, 96, 64};
constexpr int    DIv[5]   = {60, 72, 86, 86, 71};
constexpr int    DOv[5]   = {72, 86, 86, 71, 59};

__device__ __forceinline__ float gelu_f(float x) {
    // tanh-form gelu as x*sigmoid(2z); max |err| ~5e-4 (validated round 2: absmax 2e-3)
    float x2 = x * x;
    float z  = x * __builtin_fmaf(0.0356774081f, x2, 0.7978845608f);
    float e  = __expf(-2.0f * z);
    return x * __builtin_amdgcn_rcpf(e + 1.0f);
}

__device__ __forceinline__ void async_cp16(const f16* g, f16* l) {
    __builtin_amdgcn_global_load_lds((const __attribute__((address_space(1))) void*)g,
                                     (__attribute__((address_space(3))) void*)l, 16, 0, 0);
}

__device__ __forceinline__ void stage_w(const f16* __restrict__ src, f16* __restrict__ dst,
                                        int chunks, int tid) {
    int wv64 = tid & ~63;   // LDS dest must be wave-uniform base + lane*16
    for (int c0 = 0; c0 < chunks; c0 += 256) {
        int c = c0 + tid;
        if (c < chunks) async_cp16(src + (size_t)c * 8, dst + (size_t)(c0 + wv64) * 8);
    }
}

// A = W^T (m = out-feature e), B = act (n = position). D[m][n] = sum_d W^T[e][d]*act[pos][d].
// actw points at this wave's 32 position rows.
template<int KSTEPS, int MT>
__device__ __forceinline__ void layer_mm(const f16* __restrict__ actw, const f16* __restrict__ wb,
                                         f32x4 (&acc)[MT][2], int li, int q) {
#pragma unroll
    for (int mt = 0; mt < MT; mt++)
#pragma unroll
        for (int nt = 0; nt < 2; nt++) acc[mt][nt] = f32x4{0.f, 0.f, 0.f, 0.f};
#pragma unroll
    for (int ks = 0; ks < KSTEPS; ks++) {
        const int koff = ks * 32 + q * 8;
        f16x8 a[MT], b[2];
#pragma unroll
        for (int nt = 0; nt < 2; nt++)
            b[nt] = *(const f16x8*)(actw + (nt * 16 + li) * AST + koff);
#pragma unroll
        for (int mt = 0; mt < MT; mt++)
            a[mt] = *(const f16x8*)(wb + (mt * 16 + li) * AST + koff);
#pragma unroll
        for (int mt = 0; mt < MT; mt++)
#pragma unroll
            for (int nt = 0; nt < 2; nt++)
                acc[mt][nt] = __builtin_amdgcn_mfma_f32_16x16x32_f16(a[mt], b[nt], acc[mt][nt], 0, 0, 0);
    }
}

// C/D: col(n=pos)=lane&15, row(m=e)=(lane>>4)*4+r -> lane owns 4 CONSECUTIVE features of one
// position: pack gelu results into one ds_write_b64. In-place act update (rows wave-private).
template<int MT>
__device__ __forceinline__ void epilogue(f32x4 (&acc)[MT][2], f16* __restrict__ actw,
                                         const float* __restrict__ bl, int li, int q) {
#pragma unroll
    for (int mt = 0; mt < MT; mt++) {
        const int eb = mt * 16 + q * 4;
        f32x4 bb = *(const f32x4*)(bl + eb);       // same-addr across li: LDS broadcast, free
#pragma unroll
        for (int nt = 0; nt < 2; nt++) {
            union { hf16x2 h[2]; unsigned long long u; } pk;
            pk.h[0] = __builtin_amdgcn_cvt_pkrtz(gelu_f(acc[mt][nt][0] + bb[0]),
                                                 gelu_f(acc[mt][nt][1] + bb[1]));
            pk.h[1] = __builtin_amdgcn_cvt_pkrtz(gelu_f(acc[mt][nt][2] + bb[2]),
                                                 gelu_f(acc[mt][nt][3] + bb[3]));
            f16* dst = actw + (nt * 16 + li) * AST + eb;   // 8B aligned (208*pos + 2*eb)
            *(unsigned long long*)dst = pk.u;
        }
    }
}

// prep: fp32 w[k][d][e] -> fp16 W^T[k][e][d], zero-padded
__global__ __launch_bounds__(256) void prep_weights(
    const float* __restrict__ w0, const float* __restrict__ w1, const float* __restrict__ w2,
    const float* __restrict__ w3, const float* __restrict__ w4, f16* __restrict__ ws) {
    __shared__ f16 wl[86 * 86];
    const int k = blockIdx.x, l = blockIdx.y, tid = threadIdx.x;
    const float* wsrc;
    switch (l) { case 0: wsrc = w0; break; case 1: wsrc = w1; break; case 2: wsrc = w2; break;
                 case 3: wsrc = w3; break; default: wsrc = w4; }
    const int DI = DIv[l], DO = DOv[l], RW = WROWS[l];
    wsrc += (size_t)k * DI * DO;
    for (int i = tid; i < DI * DO; i += 256) wl[i] = (f16)wsrc[i];
    __syncthreads();
    f16* dst = ws + WOFF[l] + (size_t)k * RW * AST;
    const int tot = RW * AST;
    for (int i = tid; i < tot; i += 256) {
        int e = i / AST, d = i - e * AST;
        f16 v = (f16)0.f;
        if (e < DO && d < DI) v = wl[d * DO + e];
        dst[i] = v;
    }
}

__global__ __launch_bounds__(256, 3) void mlp_main(
    const float* __restrict__ x,
    const float* __restrict__ b0, const float* __restrict__ b1, const float* __restrict__ b2,
    const float* __restrict__ b3, const float* __restrict__ b4,
    const float* __restrict__ hw, const float* __restrict__ hb,
    const f16* __restrict__ ws, float* __restrict__ out) {
    extern __shared__ char smemraw[];
    f16*   act   = (f16*)smemraw;                 // [128 pos][AST]
    f16*   wbuf  = act + ACT_EL;
    float* biasl = (float*)(wbuf + WBUF_EL);      // 5 layers x 96 padded biases
    float* headl = biasl + 480;                   // 64 padded head weights

    const int tid = threadIdx.x, k = blockIdx.x, mblk = blockIdx.y;
    const int wv = tid >> 6, lane = tid & 63, li = lane & 15, q = lane >> 4;
    const int base = mblk * MTB;
    f16* actw = act + (wv * 32) * AST;            // this wave's 32 position rows

    stage_w(ws + WOFF[0] + (size_t)k * 96 * AST, wbuf, 96 * AST / 8, tid);  // async W0

    // biases (padded to 96) + head weights into LDS; overlaps with W0 staging
    for (int i = tid; i < 480; i += 256) {
        int l = i / 96, e = i - l * 96;
        const float* bg = (l == 0) ? b0 : (l == 1) ? b1 : (l == 2) ? b2 : (l == 3) ? b3 : b4;
        int DO = (l == 0) ? 72 : (l == 1) ? 86 : (l == 2) ? 86 : (l == 3) ? 71 : 59;
        biasl[i] = (e < DO) ? bg[k * DO + e] : 0.f;
    }
    if (tid < 64) headl[tid] = (tid < 59) ? hw[tid] : 0.f;

    // layer-0 activations: act[pos][d], d = c*15+j in 0..59, cols 60..63 zero (K-pad)
    for (int i = tid; i < 64 * MTB; i += 256) {
        int d = i >> 7, r = i & 127;
        int p = base + r; if (p > NPOS - 1) p = NPOS - 1;
        int b = p / NOUT, pos = p - b * NOUT;
        float v = 0.f;
        if (d < 60) { int c = d / 15, j = d - c * 15; v = x[(size_t)(b * C_ + c) * L_ + pos + j]; }
        act[r * AST + d] = (f16)v;
    }
    const float hb0 = hb[0];
    __syncthreads();

    f32x4 acc[6][2];
    layer_mm<2, 6>(actw, wbuf, acc, li, q);              // L0: K=64
    epilogue<6>(acc, actw, biasl + 0 * 96, li, q);       // no barrier: act rows wave-private
    __syncthreads();
    stage_w(ws + WOFF[1] + (size_t)k * 96 * AST, wbuf, 96 * AST / 8, tid);
    __syncthreads();
    layer_mm<3, 6>(actw, wbuf, acc, li, q);              // L1: K=96
    epilogue<6>(acc, actw, biasl + 1 * 96, li, q);
    __syncthreads();
    stage_w(ws + WOFF[2] + (size_t)k * 96 * AST, wbuf, 96 * AST / 8, tid);
    __syncthreads();
    layer_mm<3, 6>(actw, wbuf, acc, li, q);              // L2
    epilogue<6>(acc, actw, biasl + 2 * 96, li, q);
    __syncthreads();
    stage_w(ws + WOFF[3] + (size_t)k * 96 * AST, wbuf, 96 * AST / 8, tid);
    __syncthreads();
    layer_mm<3, 6>(actw, wbuf, acc, li, q);              // L3: e>=71 -> exact 0 (L4 K-pad)
    epilogue<6>(acc, actw, biasl + 3 * 96, li, q);
    __syncthreads();
    stage_w(ws + WOFF[4] + (size_t)k * 64 * AST, wbuf, 64 * AST / 8, tid);
    __syncthreads();

    // L4 + fused head: e 0..63 (4 m-tiles), gelu*hw summed in-lane, butterfly over q
    f32x4 acc4[4][2];
    layer_mm<3, 4>(actw, wbuf, acc4, li, q);
    float sum[2] = {0.f, 0.f};
#pragma unroll
    for (int mt = 0; mt < 4; mt++) {
        const int eb = mt * 16 + q * 4;
        f32x4 bb = *(const f32x4*)(biasl + 4 * 96 + eb);
        f32x4 hh = *(const f32x4*)(headl + eb);
#pragma unroll
        for (int nt = 0; nt < 2; nt++) {
#pragma unroll
            for (int r = 0; r < 4; r++)
                sum[nt] += gelu_f(acc4[mt][nt][r] + bb[r]) * hh[r];
        }
    }
#pragma unroll
    for (int nt = 0; nt < 2; nt++) {
        float s = sum[nt];
        s += __shfl_xor(s, 16);
        s += __shfl_xor(s, 32);
        s += hb0;
        if (lane < 16) {
            int p = base + wv * 32 + nt * 16 + lane;
            if (p < NPOS) {
                int b = p / NOUT, pos = p - b * NOUT;
                out[((size_t)(b * K_ + k)) * NOUT + pos] = s;
            }
        }
    }
}

extern "C" void kernel_launch(void* const* d_in, const int* in_sizes, int n_in,
                              void* d_out, int out_size, void* d_ws, size_t ws_size,
                              hipStream_t stream) {
    const float* x  = (const float*)d_in[0];
    const float* w0 = (const float*)d_in[1];  const float* b0 = (const float*)d_in[2];
    const float* w1 = (const float*)d_in[3];  const float* b1 = (const float*)d_in[4];
    const float* w2 = (const float*)d_in[5];  const float* b2 = (const float*)d_in[6];
    const float* w3 = (const float*)d_in[7];  const float* b3 = (const float*)d_in[8];
    const float* w4 = (const float*)d_in[9];  const float* b4 = (const float*)d_in[10];
    const float* hw = (const float*)d_in[11]; const float* hb = (const float*)d_in[12];
    float* out = (float*)d_out;
    f16* ws = (f16*)d_ws;   // 5.96 MB

    (void)hipFuncSetAttribute((const void*)mlp_main,
                              hipFuncAttributeMaxDynamicSharedMemorySize, (int)SMEM_BYTES);

    prep_weights<<<dim3(K_, 5), 256, 0, stream>>>(w0, w1, w2, w3, w4, ws);
    mlp_main<<<dim3(K_, NBLK), 256, SMEM_BYTES, stream>>>(x, b0, b1, b2, b3, b4, hw, hb, ws, out);
}